// Round 2
// baseline (389.653 us; speedup 1.0000x reference)
//
#include <hip/hip_runtime.h>
#include <hip/hip_bf16.h>
#include <math.h>

#define B_  512
#define DM  1024
#define DI  2048
#define DS  64
#define DTR 64
#define DT  64
#define G_  8
#define E_  4
#define DC  4

typedef __bf16 bf16x8 __attribute__((ext_vector_type(8)));
typedef float  f32x4  __attribute__((ext_vector_type(4)));
typedef unsigned short ushort_t;

__device__ __forceinline__ float bf2f(__hip_bfloat16 h) { return __bfloat162float(h); }
__device__ __forceinline__ __hip_bfloat16 f2bf(float f) { return __float2bfloat16(f); }
__device__ __forceinline__ float sigmoidf_(float x){ return 1.f/(1.f+expf(-x)); }
__device__ __forceinline__ float siluf_(float x){ return x*sigmoidf_(x); }
__device__ __forceinline__ float softplusf_(float x){ return (x>20.f)? x : log1pf(expf(x)); }

// pack two f32 -> two bf16 (RNE) in one dword
__device__ __forceinline__ unsigned int pack2(float a, float b) {
  unsigned short ua = __builtin_bit_cast(unsigned short, (__bf16)a);
  unsigned short ub = __builtin_bit_cast(unsigned short, (__bf16)b);
  return (unsigned int)ua | ((unsigned int)ub << 16);
}
__device__ __forceinline__ uint4 cvt8(float4 v0, float4 v1) {
  uint4 r;
  r.x = pack2(v0.x, v0.y); r.y = pack2(v0.z, v0.w);
  r.z = pack2(v1.x, v1.y); r.w = pack2(v1.z, v1.w);
  return r;
}

enum EpiKind { EPI_BIAS=0, EPI_G2=1, EPI_G3=2, EPI_G4=3, EPI_STORE=4 };

struct EpiParams {
  const float* bias;        // G1: b_in
  const float* conv_w;      // G2
  const float* conv_b;      // G2
  __hip_bfloat16* xs;       // G2 out / G4 in
  __hip_bfloat16* sz;       // G2 out / G4 in
  __hip_bfloat16* acat;     // G3 out (dt_r part, bf16)
  float* xdbl;              // G3 out (B,C parts, f32)
  const float* dt_bias;     // G4
  const float* dsk;         // G4 (D_skip)
  const float* bc;          // G4
  __hip_bfloat16* yout;     // G4 out
};

// C[m,n] = sum_k A[m,k] * Bw[n,k] (both row-major, K contiguous). 256 threads,
// 2x2 waves, 16x16x32 bf16 MFMA, BK=64, LDS stride BK+8 (2-way-only bank
// aliasing = free per m136). CVTA/CVTB: operand is f32 in global, converted to
// bf16 (RNE) during LDS staging.
template<int BM, int BN, int EK, bool CVTA, bool CVTB>
__global__ __launch_bounds__(256)
void gemm_bt(const void* __restrict__ Ap,
             const void* __restrict__ Bp,
             void* __restrict__ Coutp,
             int K, int N, EpiParams ep)
{
  constexpr int BK = 64;
  constexpr int SA = BK + 8;
  constexpr int WMT = BM / 32;
  constexpr int WNT = BN / 32;
  __shared__ ushort_t sA[BM*SA];
  __shared__ ushort_t sB[BN*SA];
  const int tid  = threadIdx.x;
  const int wave = tid >> 6, lane = tid & 63;
  const int wm = wave >> 1, wn = wave & 1;
  const int r = lane & 15, q = lane >> 4;
  const int bm = blockIdx.y * BM, bn = blockIdx.x * BN;

  f32x4 acc[WMT][WNT];
  #pragma unroll
  for (int i=0;i<WMT;++i)
    #pragma unroll
    for (int j=0;j<WNT;++j) acc[i][j] = (f32x4){0.f,0.f,0.f,0.f};

  for (int k0 = 0; k0 < K; k0 += BK) {
    __syncthreads();
    // ---- stage A tile ----
    for (int idx = tid*8; idx < BM*BK; idx += 256*8) {
      int row = idx >> 6, kk = idx & 63;
      if constexpr (CVTA) {
        const float* src = (const float*)Ap + (size_t)(bm+row)*K + k0 + kk;
        float4 v0 = *reinterpret_cast<const float4*>(src);
        float4 v1 = *reinterpret_cast<const float4*>(src + 4);
        *reinterpret_cast<uint4*>(&sA[row*SA + kk]) = cvt8(v0, v1);
      } else {
        const __hip_bfloat16* src = (const __hip_bfloat16*)Ap + (size_t)(bm+row)*K + k0 + kk;
        *reinterpret_cast<uint4*>(&sA[row*SA + kk]) = *reinterpret_cast<const uint4*>(src);
      }
    }
    // ---- stage B tile ----
    for (int idx = tid*8; idx < BN*BK; idx += 256*8) {
      int row = idx >> 6, kk = idx & 63;
      if constexpr (CVTB) {
        const float* src = (const float*)Bp + (size_t)(bn+row)*K + k0 + kk;
        float4 v0 = *reinterpret_cast<const float4*>(src);
        float4 v1 = *reinterpret_cast<const float4*>(src + 4);
        *reinterpret_cast<uint4*>(&sB[row*SA + kk]) = cvt8(v0, v1);
      } else {
        const __hip_bfloat16* src = (const __hip_bfloat16*)Bp + (size_t)(bn+row)*K + k0 + kk;
        *reinterpret_cast<uint4*>(&sB[row*SA + kk]) = *reinterpret_cast<const uint4*>(src);
      }
    }
    __syncthreads();
    #pragma unroll
    for (int ks = 0; ks < 2; ++ks) {
      bf16x8 af[WMT], bfr[WNT];
      #pragma unroll
      for (int mt=0; mt<WMT; ++mt)
        af[mt] = *reinterpret_cast<const bf16x8*>(&sA[(wm*(BM/2)+mt*16+r)*SA + ks*32 + q*8]);
      #pragma unroll
      for (int nt=0; nt<WNT; ++nt)
        bfr[nt] = *reinterpret_cast<const bf16x8*>(&sB[(wn*(BN/2)+nt*16+r)*SA + ks*32 + q*8]);
      #pragma unroll
      for (int mt=0; mt<WMT; ++mt)
        #pragma unroll
        for (int nt=0; nt<WNT; ++nt)
          acc[mt][nt] = __builtin_amdgcn_mfma_f32_16x16x32_bf16(af[mt], bfr[nt], acc[mt][nt], 0,0,0);
    }
  }

  #pragma unroll
  for (int mt=0; mt<WMT; ++mt) {
    #pragma unroll
    for (int nt=0; nt<WNT; ++nt) {
      #pragma unroll
      for (int i=0;i<4;++i) {
        int grow = bm + wm*(BM/2) + mt*16 + q*4 + i;
        int gcol = bn + wn*(BN/2) + nt*16 + r;
        float v = acc[mt][nt][i];
        if constexpr (EK == EPI_BIAS) {          // -> Pu (bf16 ws)
          ((__hip_bfloat16*)Coutp)[(size_t)grow*N + gcol] = f2bf(v + ep.bias[gcol]);
        } else if constexpr (EK == EPI_G2) {
          if (gcol < DI) {  // x half: conv last tap + silu
            float xc = v * ep.conv_w[gcol*DC + (DC-1)] + ep.conv_b[gcol];
            ep.xs[(size_t)grow*DI + gcol] = f2bf(siluf_(xc));
          } else {          // z half: silu(z)
            ep.sz[(size_t)grow*DI + (gcol - DI)] = f2bf(siluf_(v));
          }
        } else if constexpr (EK == EPI_G3) {
          if (gcol < DTR) ep.acat[grow*128 + gcol] = f2bf(v);   // dt_r -> A_cat[:,0:64]
          else            ep.xdbl[grow*128 + (gcol - DTR)] = v; // B,C -> f32 scratch
        } else if constexpr (EK == EPI_G4) {
          float dt  = softplusf_(v + ep.dt_bias[gcol]);
          float xsv = bf2f(ep.xs[(size_t)grow*DI + gcol]);
          float szv = bf2f(ep.sz[(size_t)grow*DI + gcol]);
          float y = (dt * xsv * ep.bc[grow] + ep.dsk[gcol] * xsv) * szv;
          ep.yout[(size_t)grow*DI + gcol] = f2bf(y);
        } else {                                  // EPI_STORE -> hk (f32 d_out)
          ((float*)Coutp)[(size_t)grow*N + gcol] = v;
        }
      }
    }
  }
}

// softmax over 4 logits, top-2 mask (ties -> lower index, matching lax.top_k),
// renormalized selected weights. All f32.
__device__ __forceinline__ void route(float t, const float* rW, const float* rb,
                                      float* w, float* mask, float* wn)
{
  float l[E_];
  float m = -1e30f;
  for (int e=0;e<E_;++e){ l[e] = t*rW[e] + rb[e]; m = fmaxf(m, l[e]); }
  float s = 0.f;
  for (int e=0;e<E_;++e){ w[e] = expf(l[e]-m); s += w[e]; }
  for (int e=0;e<E_;++e) w[e] /= s;
  int i1 = 0;
  for (int e=1;e<E_;++e) if (w[e] > w[i1]) i1 = e;
  int i2 = -1;
  for (int e=0;e<E_;++e) if (e != i1 && (i2 < 0 || w[e] > w[i2])) i2 = e;
  float ssel = w[i1] + w[i2] + 1e-8f;
  for (int e=0;e<E_;++e){
    float mk = (e==i1 || e==i2) ? 1.f : 0.f;
    mask[e] = mk;
    wn[e] = mk * w[e] / ssel;
  }
}

// One block per batch row, 64 threads. Computes both k_mote embeddings, the kan
// difference; writes expert outputs (f32) and dt_emb -> Acat[:,64:128] (bf16).
__global__ __launch_bounds__(64)
void mote_kan_kernel(const float* __restrict__ tk_c, const float* __restrict__ tk_p,
                     const float* __restrict__ rW, const float* __restrict__ rb,
                     const float* __restrict__ freq, const float* __restrict__ phase,
                     const float* __restrict__ kanW,
                     float* __restrict__ out_w, float* __restrict__ out_mask,
                     __hip_bfloat16* __restrict__ acat)
{
  const int b = blockIdx.x, tid = threadIdx.x;
  __shared__ float dphi[DT*G_];
  float t  = tk_c[b];
  float tp = tk_p[b];
  float w_c[E_], mask_c[E_], wn_c[E_];
  float w_p[E_], mask_p[E_], wn_p[E_];
  route(t,  rW, rb, w_c, mask_c, wn_c);
  route(tp, rW, rb, w_p, mask_p, wn_p);
  if (tid < E_) {
    out_w[b*E_ + tid]    = w_c[tid];
    out_mask[b*E_ + tid] = mask_c[tid];
  }
  float ec = 0.f, epv = 0.f;
  #pragma unroll
  for (int e=0;e<E_;++e) {
    float f  = freq[e*DT + tid];
    float ph = phase[e*DT + tid];
    ec  += wn_c[e] * sinf(t*f + ph);
    epv += wn_p[e] * sinf(tp*f + ph);
  }
  const float h = 2.f/(G_-1);
  #pragma unroll
  for (int g=0; g<G_; ++g) {
    float gr = -1.f + g*h;
    float a  = (ec - gr)/h;
    float bb = (epv - gr)/h;
    dphi[tid*G_ + g] = expf(-a*a) - expf(-bb*bb);
  }
  __syncthreads();
  float accv = 0.f;
  const float* kwrow = kanW + tid*DT*G_;   // kan_W[o=tid, i, g]
  for (int j=0;j<DT*G_;++j) accv += dphi[j] * kwrow[j];
  acat[b*128 + 64 + tid] = f2bf(accv);
}

// bc[b] = dot(Bmat[b], Cmat[b]) — factorized einsum('bds,bs->bd') scalar.
__global__ void bc_kernel(const float* __restrict__ xdbl, float* __restrict__ bc) {
  int b = blockIdx.x*256 + threadIdx.x;
  if (b < B_) {
    float s = 0.f;
    for (int j=0;j<DS;++j) s += xdbl[b*128 + j] * xdbl[b*128 + 64 + j];
    bc[b] = s;
  }
}

// W_cat[n, 0:64] = W_dt[n] (f32->bf16), W_cat[n, 64:128] = W_delta[n]
__global__ void pack_w_kernel(const float* __restrict__ wdt,
                              const float* __restrict__ wdel,
                              __hip_bfloat16* __restrict__ wcat) {
  int n = blockIdx.x, j = threadIdx.x;
  float v = (j < 64) ? wdt[n*64 + j] : wdel[n*64 + (j - 64)];
  wcat[n*128 + j] = f2bf(v);
}

extern "C" void kernel_launch(void* const* d_in, const int* in_sizes, int n_in,
                              void* d_out, int out_size, void* d_ws, size_t ws_size,
                              hipStream_t stream)
{
  const float* uk      = (const float*)d_in[0];
  const float* tk_c    = (const float*)d_in[1];
  const float* tk_p    = (const float*)d_in[2];
  const float* W_in    = (const float*)d_in[3];
  const float* b_in    = (const float*)d_in[4];
  const float* rW      = (const float*)d_in[5];
  const float* rb      = (const float*)d_in[6];
  const float* freq    = (const float*)d_in[7];
  const float* phase   = (const float*)d_in[8];
  const float* kanW    = (const float*)d_in[9];
  const float* W_inproj= (const float*)d_in[10];
  const float* conv_w  = (const float*)d_in[11];
  const float* conv_b  = (const float*)d_in[12];
  const float* W_x     = (const float*)d_in[13];
  const float* W_dt    = (const float*)d_in[14];
  const float* dt_bias = (const float*)d_in[15];
  const float* W_delta = (const float*)d_in[16];
  /* d_in[17] = A_log — unused by the reference math */
  const float* D_skip  = (const float*)d_in[18];
  const float* W_out   = (const float*)d_in[19];

  char* ws = (char*)d_ws;
  __hip_bfloat16* Pu   = (__hip_bfloat16*)(ws);                          // 1 MB
  __hip_bfloat16* Xs   = (__hip_bfloat16*)(ws + (size_t)(1<<20));        // 2 MB
  __hip_bfloat16* Sz   = (__hip_bfloat16*)(ws + (size_t)3*(1<<20));      // 2 MB
  __hip_bfloat16* Yb   = (__hip_bfloat16*)(ws + (size_t)5*(1<<20));      // 2 MB
  __hip_bfloat16* Acat = (__hip_bfloat16*)(ws + (size_t)7*(1<<20));                // 128 KB
  __hip_bfloat16* Wcat = (__hip_bfloat16*)(ws + (size_t)7*(1<<20) + (128<<10));    // 512 KB
  float*          Xdbl = (float*)         (ws + (size_t)7*(1<<20) + (640<<10));    // 256 KB
  float*          bc   = (float*)         (ws + (size_t)7*(1<<20) + (896<<10));    // 2 KB

  float* out_hk   = (float*)d_out;
  float* out_w    = out_hk + (size_t)B_*DM;
  float* out_mask = out_w  + (size_t)B_*E_;

  // K1: router/softmax/top2 + sin-embeddings + kan delta
  mote_kan_kernel<<<dim3(B_), dim3(64), 0, stream>>>(tk_c, tk_p, rW, rb, freq, phase, kanW,
                                                     out_w, out_mask, Acat);
  // pack [W_dt | W_delta] -> bf16
  pack_w_kernel<<<dim3(DI), dim3(128), 0, stream>>>(W_dt, W_delta, Wcat);

  // G1: pu = uk @ W_in^T + b_in  (512x1024x1024), A,B f32->bf16
  { EpiParams p{}; p.bias = b_in;
    gemm_bt<64,128,EPI_BIAS,true,true><<<dim3(DM/128, B_/64), 256, 0, stream>>>(uk, W_in, Pu, DM, DM, p); }

  // G2: xz = pu @ W_inproj^T (512x4096x1024), fused conv+silu / silu(z)
  { EpiParams p{}; p.conv_w = conv_w; p.conv_b = conv_b; p.xs = Xs; p.sz = Sz;
    gemm_bt<64,128,EPI_G2,false,true><<<dim3(2*DI/128, B_/64), 256, 0, stream>>>(Pu, W_inproj, nullptr, DM, 2*DI, p); }

  // G3: x_dbl = xs @ W_x^T (512x192x2048) -> dt_r (bf16), B/C (f32)
  { EpiParams p{}; p.acat = Acat; p.xdbl = Xdbl;
    gemm_bt<64,64,EPI_G3,false,true><<<dim3((DTR+2*DS)/64, B_/64), 256, 0, stream>>>(Xs, W_x, nullptr, DI, DTR+2*DS, p); }

  // bc[b] = dot(B_b, C_b)
  bc_kernel<<<dim3(2), dim3(256), 0, stream>>>(Xdbl, bc);

  // G4: dt GEMM (512x2048x128) + softplus + y = (dt*x*bc + D*x)*silu(z)
  { EpiParams p{}; p.dt_bias = dt_bias; p.dsk = D_skip; p.bc = bc; p.xs = Xs; p.sz = Sz; p.yout = Yb;
    gemm_bt<64,128,EPI_G4,false,false><<<dim3(DI/128, B_/64), 256, 0, stream>>>(Acat, Wcat, nullptr, 128, DI, p); }

  // G5: hk = y @ W_out^T (512x1024x2048) -> f32 d_out
  { EpiParams p{};
    gemm_bt<64,128,EPI_STORE,false,true><<<dim3(DM/128, B_/64), 256, 0, stream>>>(Yb, W_out, out_hk, DI, DM, p); }
}

// Round 3
// 185.772 us; speedup vs baseline: 2.0975x; 2.0975x over previous
//
#include <hip/hip_runtime.h>
#include <hip/hip_bf16.h>
#include <math.h>

#define B_  512
#define DM  1024
#define DI  2048
#define DS  64
#define DTR 64
#define DT  64
#define G_  8
#define E_  4
#define DC  4

typedef __bf16 bf16x8 __attribute__((ext_vector_type(8)));
typedef float  f32x4  __attribute__((ext_vector_type(4)));
typedef unsigned short ushort_t;

__device__ __forceinline__ float bf2f(__hip_bfloat16 h) { return __bfloat162float(h); }
__device__ __forceinline__ __hip_bfloat16 f2bf(float f) { return __float2bfloat16(f); }
__device__ __forceinline__ float sigmoidf_(float x){ return 1.f/(1.f+expf(-x)); }
__device__ __forceinline__ float siluf_(float x){ return x*sigmoidf_(x); }
__device__ __forceinline__ float softplusf_(float x){ return (x>20.f)? x : log1pf(expf(x)); }

__device__ __forceinline__ unsigned int pack2(float a, float b) {
  unsigned short ua = __builtin_bit_cast(unsigned short, (__bf16)a);
  unsigned short ub = __builtin_bit_cast(unsigned short, (__bf16)b);
  return (unsigned int)ua | ((unsigned int)ub << 16);
}
__device__ __forceinline__ uint4 cvt8(float4 v0, float4 v1) {
  uint4 r;
  r.x = pack2(v0.x, v0.y); r.y = pack2(v0.z, v0.w);
  r.z = pack2(v1.x, v1.y); r.w = pack2(v1.z, v1.w);
  return r;
}

enum EpiKind { EPI_PART=0, EPI_G2=1, EPI_G4=2 };

struct EpiParams {
  const float* conv_w;      // G2
  const float* conv_b;      // G2
  __hip_bfloat16* xs;       // G2 out / G4 in
  __hip_bfloat16* sz;       // G2 out / G4 in
  const float* dt_bias;     // G4
  const float* dsk;         // G4 (D_skip)
  const float* bc;          // G4
  __hip_bfloat16* yout;     // G4 out
  const float* b2;          // G4: W_delta (second K-chunk of B operand)
};

// C[m,n] = sum_k A[m,k]*B[n,k], both K-contiguous. 256 threads = 4 waves (2x2),
// wave tile 16x(BN/2), 16x16x32 bf16 MFMA, BK=64. LDS double-buffered; global
// loads issued AFTER the barrier and consumed (cvt+ds_write) AFTER the MFMA
// block, so load latency overlaps compute and no barrier drains the prefetch.
// SPLIT: blockIdx.z selects K-chunk [z*kLen, (z+1)*kLen); EPI_PART writes f32
// partials at part + z*(B_*N).
template<int BM, int BN, int EK, bool CVTA, bool CVTB, bool B2>
__global__ __launch_bounds__(256)
void gemm_bt(const void* __restrict__ Ap, const void* __restrict__ Bp,
             void* __restrict__ Coutp, int Ka, int Kb, int kLen, int N,
             EpiParams ep)
{
  constexpr int BK = 64;
  constexpr int SA = 72;                 // ushort stride; 144B rows keep 16B align
  constexpr int NA = (BM*BK)/(256*8);    // 8-elem chunks per thread for A
  constexpr int NB = (BN*BK)/(256*8);
  constexpr int WMT = (BM/2)/16;
  constexpr int WNT = (BN/2)/16;
  __shared__ ushort_t sA[2][BM*SA];
  __shared__ ushort_t sB[2][BN*SA];
  const int tid  = threadIdx.x;
  const int wave = tid >> 6, lane = tid & 63;
  const int wm = wave >> 1, wn = wave & 1;
  const int r = lane & 15, q = lane >> 4;
  const int bm = blockIdx.y * BM, bn = blockIdx.x * BN;
  const int kBase = blockIdx.z * kLen;
  const int T = kLen / BK;

  float4 fa[NA][2]; uint4 ua[NA];
  float4 fb[NB][2]; uint4 ub[NB];

  auto loadTiles = [&](int k0) {
    #pragma unroll
    for (int c=0;c<NA;++c) {
      int idx = tid*8 + c*2048; int row = idx>>6, kk = idx&63;
      if constexpr (CVTA) {
        const float* s = (const float*)Ap + (size_t)(bm+row)*Ka + k0 + kk;
        fa[c][0] = *reinterpret_cast<const float4*>(s);
        fa[c][1] = *reinterpret_cast<const float4*>(s+4);
      } else {
        const __hip_bfloat16* s = (const __hip_bfloat16*)Ap + (size_t)(bm+row)*Ka + k0 + kk;
        ua[c] = *reinterpret_cast<const uint4*>(s);
      }
    }
    #pragma unroll
    for (int c=0;c<NB;++c) {
      int idx = tid*8 + c*2048; int row = idx>>6, kk = idx&63;
      if constexpr (B2) {
        const float* bb = (k0==0) ? (const float*)Bp : ep.b2;   // [W_dt | W_delta]
        const float* s = bb + (size_t)(bn+row)*Kb + kk;
        fb[c][0] = *reinterpret_cast<const float4*>(s);
        fb[c][1] = *reinterpret_cast<const float4*>(s+4);
      } else if constexpr (CVTB) {
        const float* s = (const float*)Bp + (size_t)(bn+row)*Kb + k0 + kk;
        fb[c][0] = *reinterpret_cast<const float4*>(s);
        fb[c][1] = *reinterpret_cast<const float4*>(s+4);
      } else {
        const __hip_bfloat16* s = (const __hip_bfloat16*)Bp + (size_t)(bn+row)*Kb + k0 + kk;
        ub[c] = *reinterpret_cast<const uint4*>(s);
      }
    }
  };
  auto writeTiles = [&](int buf) {
    #pragma unroll
    for (int c=0;c<NA;++c) {
      int idx = tid*8 + c*2048; int row = idx>>6, kk = idx&63;
      uint4 v; if constexpr (CVTA) v = cvt8(fa[c][0], fa[c][1]); else v = ua[c];
      *reinterpret_cast<uint4*>(&sA[buf][row*SA + kk]) = v;
    }
    #pragma unroll
    for (int c=0;c<NB;++c) {
      int idx = tid*8 + c*2048; int row = idx>>6, kk = idx&63;
      uint4 v; if constexpr (CVTB || B2) v = cvt8(fb[c][0], fb[c][1]); else v = ub[c];
      *reinterpret_cast<uint4*>(&sB[buf][row*SA + kk]) = v;
    }
  };

  f32x4 acc[WMT][WNT];
  #pragma unroll
  for (int i=0;i<WMT;++i)
    #pragma unroll
    for (int j=0;j<WNT;++j) acc[i][j] = (f32x4){0.f,0.f,0.f,0.f};

  loadTiles(kBase);
  writeTiles(0);
  for (int t=0; t<T; ++t) {
    __syncthreads();
    const int cur = t & 1;
    if (t+1 < T) loadTiles(kBase + (t+1)*BK);   // overlaps MFMA below
    #pragma unroll
    for (int ks=0; ks<2; ++ks) {
      bf16x8 af[WMT], bfr[WNT];
      #pragma unroll
      for (int mt=0; mt<WMT; ++mt)
        af[mt] = *reinterpret_cast<const bf16x8*>(&sA[cur][(wm*(BM/2)+mt*16+r)*SA + ks*32 + q*8]);
      #pragma unroll
      for (int nt=0; nt<WNT; ++nt)
        bfr[nt] = *reinterpret_cast<const bf16x8*>(&sB[cur][(wn*(BN/2)+nt*16+r)*SA + ks*32 + q*8]);
      #pragma unroll
      for (int mt=0; mt<WMT; ++mt)
        #pragma unroll
        for (int nt=0; nt<WNT; ++nt)
          acc[mt][nt] = __builtin_amdgcn_mfma_f32_16x16x32_bf16(af[mt], bfr[nt], acc[mt][nt], 0,0,0);
    }
    if (t+1 < T) writeTiles(cur ^ 1);
  }

  #pragma unroll
  for (int mt=0; mt<WMT; ++mt) {
    #pragma unroll
    for (int nt=0; nt<WNT; ++nt) {
      #pragma unroll
      for (int i=0;i<4;++i) {
        int grow = bm + wm*(BM/2) + mt*16 + q*4 + i;
        int gcol = bn + wn*(BN/2) + nt*16 + r;
        float v = acc[mt][nt][i];
        if constexpr (EK == EPI_PART) {
          float* P = (float*)Coutp + (size_t)blockIdx.z * ((size_t)B_*N);
          P[(size_t)grow*N + gcol] = v;
        } else if constexpr (EK == EPI_G2) {
          if (gcol < DI) {  // x half: conv last tap + silu
            float xc = v * ep.conv_w[gcol*DC + (DC-1)] + ep.conv_b[gcol];
            ep.xs[(size_t)grow*DI + gcol] = f2bf(siluf_(xc));
          } else {          // z half: silu(z)
            ep.sz[(size_t)grow*DI + (gcol - DI)] = f2bf(siluf_(v));
          }
        } else {            // EPI_G4
          float dt  = softplusf_(v + ep.dt_bias[gcol]);
          float xsv = bf2f(ep.xs[(size_t)grow*DI + gcol]);
          float szv = bf2f(ep.sz[(size_t)grow*DI + gcol]);
          float y = (dt * xsv * ep.bc[grow] + ep.dsk[gcol] * xsv) * szv;
          ep.yout[(size_t)grow*DI + gcol] = f2bf(y);
        }
      }
    }
  }
}

// ---- split-K reduce kernels ----

// Pu = f2bf(sum_{s<4} part[s] + bias)
__global__ __launch_bounds__(256)
void reduce_bias_kernel(const float* __restrict__ part, const float* __restrict__ bias,
                        __hip_bfloat16* __restrict__ out)
{
  const int i = blockIdx.x*256 + threadIdx.x;       // float4 index
  const int total = B_*DM/4;
  const float4* p = (const float4*)part;
  float4 s = p[i];
  #pragma unroll
  for (int k=1;k<4;++k){ float4 t = p[i + k*total]; s.x+=t.x; s.y+=t.y; s.z+=t.z; s.w+=t.w; }
  float4 bv = ((const float4*)bias)[i & (DM/4 - 1)];
  uint2 o; o.x = pack2(s.x+bv.x, s.y+bv.y); o.y = pack2(s.z+bv.z, s.w+bv.w);
  ((uint2*)out)[i] = o;
}

// x_dbl reduce (8 splits): col<64 -> Acat[:,0:64] bf16 (dt_r); cols 64..191 are
// B,C — stash in LDS and compute bc[row] = dot(B_row, C_row) via wave reduce.
__global__ __launch_bounds__(192)
void reduce_g3_kernel(const float* __restrict__ part, __hip_bfloat16* __restrict__ acat,
                      float* __restrict__ bc)
{
  const int row = blockIdx.x, col = threadIdx.x;    // 192 threads
  const int stride = B_*192;
  float s = 0.f;
  #pragma unroll
  for (int k=0;k<8;++k) s += part[k*stride + row*192 + col];
  __shared__ float sBC[128];
  if (col < 64) acat[row*128 + col] = f2bf(s);
  else          sBC[col-64] = s;
  __syncthreads();
  if (col < 64) {
    float pval = sBC[col] * sBC[col+64];
    #pragma unroll
    for (int off=32; off; off>>=1) pval += __shfl_down(pval, off);
    if (col == 0) bc[row] = pval;
  }
}

// hk = sum_{s<4} part[s]  (f32 out)
__global__ __launch_bounds__(256)
void reduce_plain_kernel(const float* __restrict__ part, float* __restrict__ out)
{
  const int i = blockIdx.x*256 + threadIdx.x;
  const int total = B_*DM/4;
  const float4* p = (const float4*)part;
  float4 s = p[i];
  #pragma unroll
  for (int k=1;k<4;++k){ float4 t = p[i + k*total]; s.x+=t.x; s.y+=t.y; s.z+=t.z; s.w+=t.w; }
  ((float4*)out)[i] = s;
}

// ---- routing / kan ----

__device__ __forceinline__ void route(float t, const float* rW, const float* rb,
                                      float* w, float* mask, float* wn)
{
  float l[E_];
  float m = -1e30f;
  for (int e=0;e<E_;++e){ l[e] = t*rW[e] + rb[e]; m = fmaxf(m, l[e]); }
  float s = 0.f;
  for (int e=0;e<E_;++e){ w[e] = expf(l[e]-m); s += w[e]; }
  for (int e=0;e<E_;++e) w[e] /= s;
  int i1 = 0;
  for (int e=1;e<E_;++e) if (w[e] > w[i1]) i1 = e;
  int i2 = -1;
  for (int e=0;e<E_;++e) if (e != i1 && (i2 < 0 || w[e] > w[i2])) i2 = e;
  float ssel = w[i1] + w[i2] + 1e-8f;
  for (int e=0;e<E_;++e){
    float mk = (e==i1 || e==i2) ? 1.f : 0.f;
    mask[e] = mk;
    wn[e] = mk * w[e] / ssel;
  }
}

__global__ __launch_bounds__(64)
void mote_kan_kernel(const float* __restrict__ tk_c, const float* __restrict__ tk_p,
                     const float* __restrict__ rW, const float* __restrict__ rb,
                     const float* __restrict__ freq, const float* __restrict__ phase,
                     const float* __restrict__ kanW,
                     float* __restrict__ out_w, float* __restrict__ out_mask,
                     __hip_bfloat16* __restrict__ acat)
{
  const int b = blockIdx.x, tid = threadIdx.x;
  __shared__ float dphi[DT*G_];
  float t  = tk_c[b];
  float tp = tk_p[b];
  float w_c[E_], mask_c[E_], wn_c[E_];
  float w_p[E_], mask_p[E_], wn_p[E_];
  route(t,  rW, rb, w_c, mask_c, wn_c);
  route(tp, rW, rb, w_p, mask_p, wn_p);
  if (tid < E_) {
    out_w[b*E_ + tid]    = w_c[tid];
    out_mask[b*E_ + tid] = mask_c[tid];
  }
  float ec = 0.f, epv = 0.f;
  #pragma unroll
  for (int e=0;e<E_;++e) {
    float f  = freq[e*DT + tid];
    float ph = phase[e*DT + tid];
    ec  += wn_c[e] * sinf(t*f + ph);
    epv += wn_p[e] * sinf(tp*f + ph);
  }
  const float h = 2.f/(G_-1);
  #pragma unroll
  for (int g=0; g<G_; ++g) {
    float gr = -1.f + g*h;
    float a  = (ec - gr)/h;
    float bb = (epv - gr)/h;
    dphi[tid*G_ + g] = expf(-a*a) - expf(-bb*bb);
  }
  __syncthreads();
  float accv = 0.f;
  const float* kwrow = kanW + tid*DT*G_;
  for (int j=0;j<DT*G_;++j) accv += dphi[j] * kwrow[j];
  acat[b*128 + 64 + tid] = f2bf(accv);
}

extern "C" void kernel_launch(void* const* d_in, const int* in_sizes, int n_in,
                              void* d_out, int out_size, void* d_ws, size_t ws_size,
                              hipStream_t stream)
{
  const float* uk      = (const float*)d_in[0];
  const float* tk_c    = (const float*)d_in[1];
  const float* tk_p    = (const float*)d_in[2];
  const float* W_in    = (const float*)d_in[3];
  const float* b_in    = (const float*)d_in[4];
  const float* rW      = (const float*)d_in[5];
  const float* rb      = (const float*)d_in[6];
  const float* freq    = (const float*)d_in[7];
  const float* phase   = (const float*)d_in[8];
  const float* kanW    = (const float*)d_in[9];
  const float* W_inproj= (const float*)d_in[10];
  const float* conv_w  = (const float*)d_in[11];
  const float* conv_b  = (const float*)d_in[12];
  const float* W_x     = (const float*)d_in[13];
  const float* W_dt    = (const float*)d_in[14];
  const float* dt_bias = (const float*)d_in[15];
  const float* W_delta = (const float*)d_in[16];
  const float* D_skip  = (const float*)d_in[18];
  const float* W_out   = (const float*)d_in[19];

  char* ws = (char*)d_ws;
  __hip_bfloat16* Pu   = (__hip_bfloat16*)(ws);                          // 1 MB
  __hip_bfloat16* Xs   = (__hip_bfloat16*)(ws + (size_t)(1<<20));        // 2 MB
  __hip_bfloat16* Sz   = (__hip_bfloat16*)(ws + (size_t)3*(1<<20));      // 2 MB
  __hip_bfloat16* Yb   = (__hip_bfloat16*)(ws + (size_t)5*(1<<20));      // 2 MB
  __hip_bfloat16* Acat = (__hip_bfloat16*)(ws + (size_t)7*(1<<20));      // 128 KB
  float*          bc   = (float*)         (ws + (size_t)7*(1<<20) + (128<<10)); // 2 KB
  float*          Part = (float*)         (ws + (size_t)8*(1<<20));      // 8 MB (reused)

  float* out_hk   = (float*)d_out;
  float* out_w    = out_hk + (size_t)B_*DM;
  float* out_mask = out_w  + (size_t)B_*E_;

  // K1: routing + sin-embeddings + kan delta -> Acat[:,64:128], expert outputs
  mote_kan_kernel<<<dim3(B_), dim3(64), 0, stream>>>(tk_c, tk_p, rW, rb, freq, phase, kanW,
                                                     out_w, out_mask, Acat);

  // G1: pu = uk @ W_in^T (512x1024x1024), split-K x4 -> partials
  { EpiParams p{};
    gemm_bt<32,64,EPI_PART,true,true,false><<<dim3(16,16,4), 256, 0, stream>>>(
        uk, W_in, Part, DM, DM, 256, DM, p); }
  reduce_bias_kernel<<<dim3(512), 256, 0, stream>>>(Part, b_in, Pu);

  // G2: xz = pu @ W_inproj^T (512x4096x1024), fused conv+silu / silu(z)
  { EpiParams p{}; p.conv_w = conv_w; p.conv_b = conv_b; p.xs = Xs; p.sz = Sz;
    gemm_bt<32,64,EPI_G2,false,true,false><<<dim3(64,16,1), 256, 0, stream>>>(
        Pu, W_inproj, nullptr, DM, DM, DM, 2*DI, p); }

  // G3: x_dbl = xs @ W_x^T (512x192x2048), split-K x8 -> partials
  { EpiParams p{};
    gemm_bt<32,64,EPI_PART,false,true,false><<<dim3(3,16,8), 256, 0, stream>>>(
        Xs, W_x, Part, DI, DI, 256, 192, p); }
  reduce_g3_kernel<<<dim3(512), 192, 0, stream>>>(Part, Acat, bc);

  // G4: dt GEMM (512x2048x128, B = [W_dt|W_delta]) + softplus + y-fusion
  { EpiParams p{}; p.dt_bias = dt_bias; p.dsk = D_skip; p.bc = bc; p.xs = Xs; p.sz = Sz;
    p.yout = Yb; p.b2 = W_delta;
    gemm_bt<32,64,EPI_G4,false,true,true><<<dim3(32,16,1), 256, 0, stream>>>(
        Acat, W_dt, nullptr, 128, 64, 128, DI, p); }

  // G5: hk = y @ W_out^T (512x1024x2048), split-K x4 -> partials
  { EpiParams p{};
    gemm_bt<32,64,EPI_PART,false,true,false><<<dim3(16,16,4), 256, 0, stream>>>(
        Yb, W_out, Part, DI, DI, 512, DM, p); }
  reduce_plain_kernel<<<dim3(512), 256, 0, stream>>>(Part, out_hk);
}